// Round 9
// baseline (469.223 us; speedup 1.0000x reference)
//
#include <hip/hip_runtime.h>
#include <cstddef>
#include <cstdint>

#define BATCH_N 32768
#define OUT_DIM 10
#define HS 524288

typedef unsigned short u16;
typedef __attribute__((ext_vector_type(8))) _Float16 half8;
typedef __attribute__((ext_vector_type(4))) float f32x4;

__device__ __forceinline__ u16 f2h(float v) {
    _Float16 h = (_Float16)v;                 // RTN
    return __builtin_bit_cast(u16, h);
}
__device__ __forceinline__ float h2f(u16 h) {
    return (float)__builtin_bit_cast(_Float16, h);
}
__device__ __forceinline__ float tanh_fast(float x) {
    float e = __expf(2.f * x);        // inf -> 1, 0 -> -1 : robust
    return 1.f - 2.f / (e + 1.f);
}

// ============================================================================
// MEGA-FUSED NETWORK KERNEL — R13/R14 version verbatim (243us control).
// ============================================================================
__global__ __launch_bounds__(1024, 4)
void meganet(const float* __restrict__ X,
             const u16* __restrict__ Wi,        // [256 u][800 k] f16
             const float* __restrict__ b_in,
             const u16* __restrict__ Wc,        // [8][512 c][512 k] f16
             const float* __restrict__ cc,      // [8][512]: [0..255]=c0, [256..511]=c1
             const u16* __restrict__ WoT,       // [16 o][256 k] f16 (W_out^T, padded)
             const float* __restrict__ bo,
             float* __restrict__ out)
{
    __shared__ u16 state[65536];     // 128 KB
    __shared__ float aux[4096];      // 16 KB: x double-buffer
    const int t = threadIdx.x;
    const int wave = t >> 6, lane = t & 63;
    const int fl = lane & 15, kq = lane >> 4;
    const int b0 = blockIdx.x * 128;

    // ---------------- input stage: v0 = x @ W_in + b_in (K=784, pad 800) ----
    f32x4 ai[8];
#pragma unroll
    for (int a = 0; a < 8; ++a) ai[a] = (f32x4){0.f, 0.f, 0.f, 0.f};

    const u16* bpIn = Wi + (size_t)(wave * 16 + fl) * 800 + kq * 8;

    u16* xbuf = (u16*)aux;           // 2 x 4096 u16 chunk buffers
    const int xr = t >> 3;           // row 0..127
    const int xk = (t & 7) * 4;      // 0..28 step 4
    const size_t xrow = (size_t)(b0 + xr) * 784;
    const int xoff = (xr >> 4) * 512 + ((xk >> 3) * 16 + (xr & 15)) * 8 + (xk & 7);

    half8 IB[2];
    float4 xa;
    {   // prologue: chunk0 -> buf0
        float4 x0 = *(const float4*)(X + xrow + xk);
        ushort4 h;
        h.x = f2h(x0.x); h.y = f2h(x0.y); h.z = f2h(x0.z); h.w = f2h(x0.w);
        *(ushort4*)&xbuf[xoff] = h;
        xa = *(const float4*)(X + xrow + 32 + xk);     // chunk 1
        IB[0] = *(const half8*)(bpIn);                 // chunk 0 weights
    }

#pragma unroll
    for (int ki = 0; ki < 25; ++ki) {
        const int cur = ki & 1, nxt = cur ^ 1;
        __syncthreads();                 // buf[cur] ready; buf[nxt] reads done
        if (ki < 24) {                   // stage chunk ki+1 into buf[nxt]
            ushort4 h;
            h.x = f2h(xa.x); h.y = f2h(xa.y); h.z = f2h(xa.z); h.w = f2h(xa.w);
            *(ushort4*)&xbuf[nxt * 4096 + xoff] = h;
            if (ki < 23) {               // load chunk ki+2 (depth-2)
                const int gk = (ki + 2) * 32 + xk;
                const int ga = (gk <= 780) ? gk : 780;   // Wi packs 0 for k>=784
                xa = *(const float4*)(X + xrow + ga);
            }
            IB[nxt] = *(const half8*)(bpIn + (ki + 1) * 32);
        }
        const u16* rb = xbuf + cur * 4096;
#pragma unroll
        for (int mt = 0; mt < 8; ++mt) {
            half8 af = *(const half8*)&rb[mt * 512 + lane * 8];
            ai[mt] = __builtin_amdgcn_mfma_f32_16x16x32_f16(af, IB[cur], ai[mt], 0, 0, 0);
        }
    }

    // layer-0 ks=0 weight prefetch: global, independent of LDS -> issue early
    const u16* bp0 = Wc + (size_t)(wave * 16 + fl) * 512 + kq * 8;   // z0 row u
    const u16* bp1 = bp0 + 131072;                                   // z1 row u
    half8 B[2][2];
    B[0][0] = *(const half8*)(bp0);
    B[0][1] = *(const half8*)(bp1);

    // input epilogue: state v0 (k=u), w = 2*tanh(v0) (k=256+u)
    {
        const float bi = b_in[wave * 16 + fl];
        const int u = wave * 16 + fl;
        const int slab = u >> 5;
        const int cbase = ((u >> 3) & 3) * 128 + (u & 7);
#pragma unroll
        for (int mt = 0; mt < 8; ++mt) {
#pragma unroll
            for (int r = 0; r < 4; ++r) {
                float v = ai[mt][r] + bi;
                float w = 2.f * tanh_fast(v);
                const int base = mt * 512 + (kq * 4 + r) * 8 + cbase;
                state[slab * 4096 + base] = f2h(v);
                state[(8 + slab) * 4096 + base] = f2h(w);
            }
        }
    }

    // ---------------- 8 implicit layers ----------------
    for (int L = 0; L < 8; ++L) {
        const float ccv0 = cc[L * 512 + wave * 16 + fl];
        const float ccv1 = cc[L * 512 + 256 + wave * 16 + fl];
        f32x4 acc[8][2];
#pragma unroll
        for (int a = 0; a < 8; ++a) {
            acc[a][0] = (f32x4){0.f, 0.f, 0.f, 0.f};
            acc[a][1] = (f32x4){0.f, 0.f, 0.f, 0.f};
        }
        __syncthreads();   // state ready
#pragma unroll
        for (int ks = 0; ks < 16; ++ks) {
            const int cur = ks & 1, nxt = cur ^ 1;
            if (ks < 15) {             // prefetch next K-step (2 x 16B)
                B[nxt][0] = *(const half8*)(bp0 + (ks + 1) * 32);
                B[nxt][1] = *(const half8*)(bp1 + (ks + 1) * 32);
            } else {                   // prefetch next layer's ks=0 across epilogue
                bp0 += 262144; bp1 += 262144;
                if (L < 7) {
                    B[nxt][0] = *(const half8*)(bp0);
                    B[nxt][1] = *(const half8*)(bp1);
                }
            }
#pragma unroll
            for (int mt = 0; mt < 8; ++mt) {
                half8 af = *(const half8*)&state[ks * 4096 + mt * 512 + lane * 8];
                acc[mt][0] = __builtin_amdgcn_mfma_f32_16x16x32_f16(af, B[cur][0], acc[mt][0], 0, 0, 0);
                acc[mt][1] = __builtin_amdgcn_mfma_f32_16x16x32_f16(af, B[cur][1], acc[mt][1], 0, 0, 0);
            }
        }
        __syncthreads();   // all state reads done; safe to overwrite
        // epilogue: thread owns z0[u] and z1[u] -> tanh once, no shfl
        {
            const int u = wave * 16 + fl;
            const int slab = u >> 5;
            const int cbase = ((u >> 3) & 3) * 128 + (u & 7);
#pragma unroll
            for (int mt = 0; mt < 8; ++mt) {
#pragma unroll
                for (int r = 0; r < 4; ++r) {
                    float z0 = acc[mt][0][r] + ccv0;
                    float z1 = acc[mt][1][r] + ccv1;
                    float tv = tanh_fast(z0);
                    const int base = mt * 512 + (kq * 4 + r) * 8 + cbase;
                    state[slab * 4096 + base] = f2h(z0);
                    state[(8 + slab) * 4096 + base] = f2h(z1 + tv);
                }
            }
        }
    }

    // ---------------- output stage: out = v0 @ W_out + b_out via MFMA ------
    __syncthreads();
    if (wave < 8) {
        const u16* wp = WoT + fl * 256 + kq * 8;   // B-frag: col=fl, k=kq*8+j
        f32x4 oa = (f32x4){0.f, 0.f, 0.f, 0.f};
#pragma unroll
        for (int ks = 0; ks < 8; ++ks) {           // v0 = state k<256
            half8 af = *(const half8*)&state[ks * 4096 + wave * 512 + lane * 8];
            half8 bf = *(const half8*)(wp + ks * 32);
            oa = __builtin_amdgcn_mfma_f32_16x16x32_f16(af, bf, oa, 0, 0, 0);
        }
        if (fl < 10) {
            const float bv = bo[fl];
#pragma unroll
            for (int r = 0; r < 4; ++r)
                out[(size_t)(b0 + wave * 16 + kq * 4 + r) * 10 + fl] = oa[r] + bv;
        }
    }
}

// ============================================================================
// R15 prep: 5 dispatches total (vs 11).  Evidence: prep time invariant at
// ~19-20us/dispatch across 4 structurally different implementations (R11-R14)
// -> serial dispatch COUNT is the cost.  Every NS iterate is a polynomial in
// symmetric C -> symmetric -> columns readable as rows; this enables:
//  * ns_fused: one dispatch per NS iteration (col-strip W=8: Y-strip then
//    X'-strip in one block, cross-wave K-split reduced through LDS).
//  * pqr_pack: P,Q,R + ENTIRE Wc pack + cc in one dispatch (Q=P^T, R=R^T,
//    M=M^T make all pack operands block-local).
//  * Bt transpose eliminated (B^T cols = B rows).
// Chain: k1 -> ns1 -> ns2 -> ns3 -> pqr_pack -> meganet.
// ============================================================================

// ---- k1 tile: C = B0^T B0 + 2I, Gershgorin rowsum partials (plain stores) --
__device__ void ctile64(const float* __restrict__ B0, float* __restrict__ C,
                        float* __restrict__ scr, int i, int u0, int v0)
{
    __shared__ float As[16][64];
    __shared__ float Bs[16][64];
    const size_t off = (size_t)i * 65536;
    const int t  = threadIdx.x;
    const int tx = t & 15, ty = t >> 4;
    const int lk = t >> 4, lv = (t & 15) << 2;

    float acc[4][4];
#pragma unroll
    for (int m = 0; m < 4; ++m)
#pragma unroll
        for (int n = 0; n < 4; ++n) acc[m][n] = 0.f;

    float4 an = *(const float4*)(B0 + off + (size_t)lk * 256 + u0 + lv);
    float4 bn = *(const float4*)(B0 + off + (size_t)lk * 256 + v0 + lv);

    for (int k0 = 0; k0 < 256; k0 += 16) {
        if (k0) __syncthreads();
        *(float4*)&As[lk][lv] = an;
        *(float4*)&Bs[lk][lv] = bn;
        if (k0 < 240) {
            an = *(const float4*)(B0 + off + (size_t)(k0 + 16 + lk) * 256 + u0 + lv);
            bn = *(const float4*)(B0 + off + (size_t)(k0 + 16 + lk) * 256 + v0 + lv);
        }
        __syncthreads();
#pragma unroll
        for (int kk = 0; kk < 16; ++kk) {
            float af[4], bf[4];
            *(float4*)&af[0] = *(const float4*)&As[kk][ty * 4];
            *(float4*)&bf[0] = *(const float4*)&Bs[kk][tx * 4];
#pragma unroll
            for (int m = 0; m < 4; ++m)
#pragma unroll
                for (int n = 0; n < 4; ++n) acc[m][n] += af[m] * bf[n];
        }
    }

#pragma unroll
    for (int m = 0; m < 4; ++m) {
        const int u = u0 + ty * 4 + m;
        const size_t idx = off + (size_t)u * 256 + v0 + tx * 4;
        float4 r; float* rf = &r.x;
#pragma unroll
        for (int n = 0; n < 4; ++n)
            rf[n] = acc[m][n] + ((u == v0 + tx * 4 + n) ? 2.f : 0.f);
        *(float4*)&C[idx] = r;
        float s = fabsf(rf[0]) + fabsf(rf[1]) + fabsf(rf[2]) + fabsf(rf[3]);
        s += __shfl_xor(s, 1); s += __shfl_xor(s, 2);
        s += __shfl_xor(s, 4); s += __shfl_xor(s, 8);
        if (tx == 0) scr[(i * 4 + (v0 >> 6)) * 256 + u] = s;
    }
}

// K1: C (+rowsum partials) | Wi transpose-pack | WoT pack  (329 blocks)
__launch_bounds__(256)
__global__ void k1_fused(const float* __restrict__ B0, const float* __restrict__ W_in,
                         const float* __restrict__ W_out,
                         float* __restrict__ C, u16* __restrict__ Wi,
                         u16* __restrict__ WoT, float* __restrict__ scr)
{
    const int b = blockIdx.x;
    const int t = threadIdx.x;
    if (b < 128) {
        const int i = b >> 4, tile = b & 15;
        ctile64(B0, C, scr, i, (tile >> 2) * 64, (tile & 3) * 64);
        return;
    }
    if (b < 328) {                        // Wi pack: 200 blocks
        __shared__ float tl[32][33];
        const int tx = t & 31, ty = t >> 5;
        const int bb = b - 128;           // 25 k-tiles x 8 u-tiles
        const int k0 = (bb % 25) * 32, u0 = (bb / 25) * 32;
#pragma unroll
        for (int r = 0; r < 32; r += 8) {
            const int k = k0 + ty + r;
            tl[ty + r][tx] = (k < 784) ? W_in[(size_t)k * 256 + u0 + tx] : 0.f;
        }
        __syncthreads();
#pragma unroll
        for (int r = 0; r < 32; r += 8)
            Wi[(size_t)(u0 + ty + r) * 800 + k0 + tx] = f2h(tl[tx][ty + r]);
    } else {                              // WoT pack: [16 o][256 k]
        for (int idx = t; idx < 4096; idx += 256) {
            const int o = idx >> 8, k = idx & 255;
            WoT[o * 256 + k] = f2h((o < 10) ? W_out[(size_t)k * 10 + o] : 0.f);
        }
    }
}

// ---- strip GEMM core: per-thread partial of G = A(rows) * S(LDS strip) ----
// thread: rq = lane (rows 4rq..4rq+3), kq = wave (k in kq*64..+63)
__device__ __forceinline__ void strip_mm(const float* __restrict__ A,
                                         const float (*S)[8], float acc[4][8],
                                         int rq, int kq)
{
#pragma unroll
    for (int m = 0; m < 4; ++m)
#pragma unroll
        for (int n = 0; n < 8; ++n) acc[m][n] = 0.f;
    const int k0 = kq * 64;
#pragma unroll 4
    for (int k = k0; k < k0 + 64; k += 4) {
        float4 a0 = *(const float4*)(A + (size_t)(4 * rq + 0) * 256 + k);
        float4 a1 = *(const float4*)(A + (size_t)(4 * rq + 1) * 256 + k);
        float4 a2 = *(const float4*)(A + (size_t)(4 * rq + 2) * 256 + k);
        float4 a3 = *(const float4*)(A + (size_t)(4 * rq + 3) * 256 + k);
#pragma unroll
        for (int kk = 0; kk < 4; ++kk) {
            float4 sl = *(const float4*)&S[k + kk][0];
            float4 sh = *(const float4*)&S[k + kk][4];
            const float* sp0 = &sl.x; const float* sp1 = &sh.x;
            float av[4];
            av[0] = ((const float*)&a0)[kk]; av[1] = ((const float*)&a1)[kk];
            av[2] = ((const float*)&a2)[kk]; av[3] = ((const float*)&a3)[kk];
#pragma unroll
            for (int m = 0; m < 4; ++m) {
#pragma unroll
                for (int n = 0; n < 4; ++n) {
                    acc[m][n]     += av[m] * sp0[n];
                    acc[m][4 + n] += av[m] * sp1[n];
                }
            }
        }
    }
}

// write partials, sync, sum 4 waves' quarters -> g[8] for row t
__device__ __forceinline__ void strip_reduce(float (*red)[256][8], float acc[4][8],
                                             int rq, int kq, int t, float g[8])
{
#pragma unroll
    for (int m = 0; m < 4; ++m) {
        *(float4*)&red[kq][4 * rq + m][0] = *(const float4*)&acc[m][0];
        *(float4*)&red[kq][4 * rq + m][4] = *(const float4*)&acc[m][4];
    }
    __syncthreads();
#pragma unroll
    for (int n = 0; n < 8; ++n)
        g[n] = red[0][t][n] + red[1][t][n] + red[2][t][n] + red[3][t][n];
}

// ---- fused NS iteration: one dispatch, grid (32 strips, 8 matrices) -------
// IT==1: X1 = 2aI + 2bC - a*Y - b*C*Y,  Y = aC + b*C*C   (X0 = aI+bC virtual)
// IT==2: X' = 2X - X*(C*X)
template<int IT>
__launch_bounds__(256)
__global__ void ns_fused(const float* __restrict__ C, const float* __restrict__ Xin,
                         float* __restrict__ Xout, const float* __restrict__ scr)
{
    __shared__ float Sc[256][8];
    __shared__ float Yc[256][8];
    __shared__ float red[4][256][8];
    const int i = blockIdx.y;
    const int j0 = blockIdx.x * 8;
    const int t = threadIdx.x;
    const int rq = t & 63, kq = t >> 6;
    const size_t off = (size_t)i * 65536;
    const float* Cm = C + off;

    float ca = 0.f, cb = 0.f;
    if (IT == 1) {                     // NS seed coeffs from rowsum partials
        float* r0 = &red[0][0][0];
        float s = scr[i * 1024 + t] + scr[i * 1024 + 256 + t]
                + scr[i * 1024 + 512 + t] + scr[i * 1024 + 768 + t];
        r0[t] = s;
        __syncthreads();
        for (int o = 128; o >= 1; o >>= 1) {
            if (t < o) r0[t] = fmaxf(r0[t], r0[t + o]);
            __syncthreads();
        }
        const float bt_ = r0[0];       // >= lambda_max; lambda_min >= 2
        const float r = (2.f + bt_) * (2.f + bt_) / (8.f * bt_);
        const float e = (r - 1.f) / (r + 1.f);
        cb = -(1.f - e) / (2.f * bt_);
        ca = -cb * (2.f + bt_);
        __syncthreads();
    }

    // stage strip S[k][j] = Src[j0+j][k]  (Src symmetric -> rows are cols)
    {
        const float* src = (IT == 1) ? Cm : (Xin + off);
        const int jr = t >> 5;            // 0..7
        const int kb = (t & 31) * 8;
        float4 v0 = *(const float4*)(src + (size_t)(j0 + jr) * 256 + kb);
        float4 v1 = *(const float4*)(src + (size_t)(j0 + jr) * 256 + kb + 4);
        Sc[kb + 0][jr] = v0.x; Sc[kb + 1][jr] = v0.y;
        Sc[kb + 2][jr] = v0.z; Sc[kb + 3][jr] = v0.w;
        Sc[kb + 4][jr] = v1.x; Sc[kb + 5][jr] = v1.y;
        Sc[kb + 6][jr] = v1.z; Sc[kb + 7][jr] = v1.w;
    }
    __syncthreads();

    float acc[4][8], g[8];
    // phase 1: G1 = C * Sc
    strip_mm(Cm, Sc, acc, rq, kq);
    strip_reduce(red, acc, rq, kq, t, g);
#pragma unroll
    for (int n = 0; n < 8; ++n)
        Yc[t][n] = (IT == 1) ? (ca * Sc[t][n] + cb * g[n]) : g[n];
    __syncthreads();

    // phase 2: G2 = A2 * Yc   (A2 = C for IT1, X for IT2)
    const float* A2 = (IT == 1) ? Cm : (Xin + off);
    strip_mm(A2, Yc, acc, rq, kq);
    strip_reduce(red, acc, rq, kq, t, g);

    float o8[8];
#pragma unroll
    for (int n = 0; n < 8; ++n) {
        if (IT == 1) {
            const float dg = (t == j0 + n) ? 1.f : 0.f;
            o8[n] = 2.f * ca * dg + 2.f * cb * Sc[t][n] - ca * Yc[t][n] - cb * g[n];
        } else {
            o8[n] = 2.f * Sc[t][n] - g[n];
        }
    }
    *(float4*)(Xout + off + (size_t)t * 256 + j0)     = *(const float4*)&o8[0];
    *(float4*)(Xout + off + (size_t)t * 256 + j0 + 4) = *(const float4*)&o8[4];
}

// ---- fused P,Q,R + full Wc pack + cc: one dispatch (264 blocks) -----------
// strip block: Pc = M*B^Tc, Qc = B*Mc, Rc = B*Pc; pack rows u in strip via
// Q = P^T, R = R^T, M = M^T (all pack operands in LDS).
__launch_bounds__(256)
__global__ void pqr_pack(const float* __restrict__ M, const float* __restrict__ B0,
                         const float* __restrict__ q, float* __restrict__ cc,
                         u16* __restrict__ Wc)
{
    __shared__ float BtRc[256][8];    // Btc in P-phase, Rc after
    __shared__ float Mc[256][8];
    __shared__ float Pc[256][8];
    __shared__ float Qc[256][8];
    __shared__ float red[4][256][8];
    const int b = blockIdx.x;
    const int t = threadIdx.x;

    if (b >= 256) {                   // cc for matrix i = b-256
        float* qs = &red[0][0][0]; float* vs = qs + 256; float* c1s = vs + 256;
        const int i = b - 256;
        const int u = t;
        const size_t ob = (size_t)i * 65536;
        qs[u] = q[i * 256 + u];
        __syncthreads();
        float s0 = 0.f;
        for (int k = 0; k < 256; ++k) s0 += B0[ob + (size_t)k * 256 + u] * qs[k];
        vs[u] = 0.1f * s0;
        __syncthreads();
        float s = 0.f;
        for (int k = 0; k < 256; ++k) s += M[ob + (size_t)k * 256 + u] * vs[k];
        c1s[u] = s;
        cc[i * 512 + 256 + u] = s;
        __syncthreads();
        float s2 = 0.f;
        for (int k = 0; k < 256; ++k) s2 += B0[ob + (size_t)u * 256 + k] * c1s[k];
        cc[i * 512 + u] = 0.1f * qs[u] - s2;
        return;
    }

    const int i = b >> 5;
    const int j0 = (b & 31) * 8;
    const int rq = t & 63, kq = t >> 6;
    const size_t off = (size_t)i * 65536;
    const float* Mm = M + off;
    const float* Bm = B0 + off;

    // stage Btc[k][j] = B0[j0+j][k]  and  Mc[k][j] = M[j0+j][k] (M sym)
    {
        const int jr = t >> 5;
        const int kb = (t & 31) * 8;
        float4 b0v = *(const float4*)(Bm + (size_t)(j0 + jr) * 256 + kb);
        float4 b1v = *(const float4*)(Bm + (size_t)(j0 + jr) * 256 + kb + 4);
        BtRc[kb + 0][jr] = b0v.x; BtRc[kb + 1][jr] = b0v.y;
        BtRc[kb + 2][jr] = b0v.z; BtRc[kb + 3][jr] = b0v.w;
        BtRc[kb + 4][jr] = b1v.x; BtRc[kb + 5][jr] = b1v.y;
        BtRc[kb + 6][jr] = b1v.z; BtRc[kb + 7][jr] = b1v.w;
        float4 m0v = *(const float4*)(Mm + (size_t)(j0 + jr) * 256 + kb);
        float4 m1v = *(const float4*)(Mm + (size_t)(j0 + jr) * 256 + kb + 4);
        Mc[kb + 0][jr] = m0v.x; Mc[kb + 1][jr] = m0v.y;
        Mc[kb + 2][jr] = m0v.z; Mc[kb + 3][jr] = m0v.w;
        Mc[kb + 4][jr] = m1v.x; Mc[kb + 5][jr] = m1v.y;
        Mc[kb + 6][jr] = m1v.z; Mc[kb + 7][jr] = m1v.w;
    }
    __syncthreads();

    float acc[4][8], g[8];
    // P = M * B^T : Pc[r][j] = sum_k M[r][k] * Btc[k][j]
    strip_mm(Mm, BtRc, acc, rq, kq);
    strip_reduce(red, acc, rq, kq, t, g);
#pragma unroll
    for (int n = 0; n < 8; ++n) Pc[t][n] = g[n];
    __syncthreads();
    // Q = B * M : Qc[r][j] = sum_k B0[r][k] * Mc[k][j]
    strip_mm(Bm, Mc, acc, rq, kq);
    strip_reduce(red, acc, rq, kq, t, g);
#pragma unroll
    for (int n = 0; n < 8; ++n) Qc[t][n] = g[n];
    __syncthreads();
    // R = B * P : Rc[r][j] = sum_k B0[r][k] * Pc[k][j]
    strip_mm(Bm, Pc, acc, rq, kq);
    strip_reduce(red, acc, rq, kq, t, g);
    __syncthreads();                 // BtRc reads (staging) long done; reuse
#pragma unroll
    for (int n = 0; n < 8; ++n) BtRc[t][n] = g[n];   // Rc
    __syncthreads();

    // pack rows u = j0+ul:
    //  z0 row u:  [k<256: I - R[u][k] = d - Rc[k][ul] | k>=256: -Q[u][m] = -Pc[m][ul]]
    //  z1 row 256+u: [P[u][m] = Qc[m][ul] | M[u][m] = Mc[m][ul]]
    {
        const int ul = t >> 5;
        const int u = j0 + ul;
        const int kb = (t & 31) * 16;
        u16* w0 = Wc + (size_t)i * 262144 + (size_t)u * 512;
        u16* w1 = Wc + (size_t)i * 262144 + (size_t)(256 + u) * 512;
#pragma unroll
        for (int n = 0; n < 16; ++n) {
            const int k = kb + n;
            float v0, v1;
            if (k < 256) {
                v0 = ((u == k) ? 1.f : 0.f) - BtRc[k][ul];
                v1 = Qc[k][ul];
            } else {
                v0 = -Pc[k - 256][ul];
                v1 = Mc[k - 256][ul];
            }
            w0[k] = f2h(v0);
            w1[k] = f2h(v1);
        }
    }
}

extern "C" void kernel_launch(void* const* d_in, const int* in_sizes, int n_in,
                              void* d_out, int out_size, void* d_ws, size_t ws_size,
                              hipStream_t stream)
{
    const float* x     = (const float*)d_in[0];
    const float* W_in  = (const float*)d_in[1];
    const float* b_in  = (const float*)d_in[2];
    const float* B0    = (const float*)d_in[3];
    const float* q     = (const float*)d_in[4];
    const float* W_out = (const float*)d_in[5];
    const float* b_out = (const float*)d_in[6];

    u16* Wc  = (u16*)d_ws;                 // 8 * 262144 u16 = 4 MB
    u16* Wi  = Wc + 8 * 262144;            // 256*800 u16
    u16* WoT = Wi + 204800;                // 16*256 u16
    float* cc = (float*)(WoT + 4096);      // 8*512 floats
    float* F  = cc + 4096;
    float* Cm = F;                         // 8 x 64K floats
    float* Xa = F + 1 * HS;
    float* Xb = F + 2 * HS;
    float* scr = F + 3 * HS;               // 8192 floats (rowsum partials)

    // K1: C = B0^T B0 + 2I (+rowsum partials) | Wi | WoT
    k1_fused<<<329, 256, 0, stream>>>(B0, W_in, W_out, Cm, Wi, WoT, scr);
    // NS iterations, one dispatch each (X0 virtual in iter 1):
    ns_fused<1><<<dim3(32, 8), 256, 0, stream>>>(Cm, nullptr, Xa, scr);  // X1
    ns_fused<2><<<dim3(32, 8), 256, 0, stream>>>(Cm, Xa, Xb, nullptr);   // X2
    ns_fused<2><<<dim3(32, 8), 256, 0, stream>>>(Cm, Xb, Xa, nullptr);   // M
    // P,Q,R + full Wc pack + cc in one dispatch:
    pqr_pack<<<264, 256, 0, stream>>>(Xa, B0, q, cc, Wc);

    // ---- the whole network in one kernel ----
    meganet<<<BATCH_N / 128, 1024, 0, stream>>>(
        x, Wi, b_in, Wc, cc, WoT, b_out, (float*)d_out);
}

// Round 10
// 466.088 us; speedup vs baseline: 1.0067x; 1.0067x over previous
//
#include <hip/hip_runtime.h>
#include <cstddef>
#include <cstdint>

#define BATCH_N 32768
#define OUT_DIM 10
#define HS 524288   // partial-buffer stride in floats (8 matrices x 65536)

typedef unsigned short u16;
typedef __attribute__((ext_vector_type(8))) _Float16 half8;
typedef __attribute__((ext_vector_type(4))) float f32x4;
typedef __attribute__((ext_vector_type(16))) float f32x16;

__device__ __forceinline__ u16 f2h(float v) {
    _Float16 h = (_Float16)v;                 // RTN
    return __builtin_bit_cast(u16, h);
}
__device__ __forceinline__ float h2f(u16 h) {
    return (float)__builtin_bit_cast(_Float16, h);
}
__device__ __forceinline__ float tanh_fast(float x) {
    float e = __expf(2.f * x);        // inf -> 1, 0 -> -1 : robust
    return 1.f - 2.f / (e + 1.f);
}

// ============================================================================
// MEGA-FUSED NETWORK KERNEL (R16: layer loop on mfma_f32_32x32x16_f16).
// Rationale: layer loop was LDS-pipe-bound (2048 ds_read_b128/CU/layer, 16x
// wave redundancy on the A-panel).  32x32x16 doubles FLOP per LDS byte at
// the SAME register budget (acc = 4 x f32x16 = 64 AGPR, B ping-pong 16 VGPR
// = R8's proven 128/wave).  Layer LDS: 2048 -> 1024 reads/CU/layer.
// Wave = (rg 0..1: 64 rows) x (cg 0..7: 32 u-cols, z0+z1 tiles).
// State layout: [ks 0..31][row-tile 0..3][512]: elem (m,k) at
//   (k>>4)*2048 + (m>>5)*512 + ((k>>3)&1)*256 + (m&31)*8 + (k&7)
// so a 32x32x16 A-frag read is "tilebase + lane*8" (conflict-free b128).
// Wc layout: [L][tile 0..15][ks 0..31][512]; tile<8 = z0 cols 32cg..+31,
// tile>=8 = z1; elem (col c, k) at ((k>>3)&1)*256 + (c&31)*8 + (k&7).
// A/B lane maps follow the verified gfx950 2xK pattern (contiguous 8,
// k-half = lane>>5); C/D: col=lane&31, row=(reg&3)+8*(reg>>2)+4*(lane>>5).
// ============================================================================
__global__ __launch_bounds__(1024, 4)
void meganet(const float* __restrict__ X,
             const u16* __restrict__ Wi,        // [256 u][800 k] f16
             const float* __restrict__ b_in,
             const u16* __restrict__ Wc,        // [8][16][32][512] f16
             const float* __restrict__ cc,      // [8][512]: [0..255]=c0, [256..511]=c1
             const u16* __restrict__ WoT,       // [16 ks][512] f16 B-frag pack
             const float* __restrict__ bo,
             float* __restrict__ out)
{
    __shared__ u16 state[65536];     // 128 KB
    __shared__ float aux[4096];      // 16 KB: x double-buffer
    const int t = threadIdx.x;
    const int wave = t >> 6, lane = t & 63;
    const int fl = lane & 15, kq = lane >> 4;
    const int b0 = blockIdx.x * 128;

    // ---------------- input stage: v0 = x @ W_in + b_in (K=784, pad 800) ----
    // unchanged R8 structure (16x16x32, xbuf-private fragment layout)
    f32x4 ai[8];
#pragma unroll
    for (int a = 0; a < 8; ++a) ai[a] = (f32x4){0.f, 0.f, 0.f, 0.f};

    const u16* bpIn = Wi + (size_t)(wave * 16 + fl) * 800 + kq * 8;

    u16* xbuf = (u16*)aux;           // 2 x 4096 u16 chunk buffers
    const int xr = t >> 3;           // row 0..127
    const int xk = (t & 7) * 4;      // 0..28 step 4
    const size_t xrow = (size_t)(b0 + xr) * 784;
    const int xoff = (xr >> 4) * 512 + ((xk >> 3) * 16 + (xr & 15)) * 8 + (xk & 7);

    half8 IB[2];
    float4 xa;
    {   // prologue: chunk0 -> buf0
        float4 x0 = *(const float4*)(X + xrow + xk);
        ushort4 h;
        h.x = f2h(x0.x); h.y = f2h(x0.y); h.z = f2h(x0.z); h.w = f2h(x0.w);
        *(ushort4*)&xbuf[xoff] = h;
        xa = *(const float4*)(X + xrow + 32 + xk);     // chunk 1
        IB[0] = *(const half8*)(bpIn);                 // chunk 0 weights
    }

#pragma unroll
    for (int ki = 0; ki < 25; ++ki) {
        const int cur = ki & 1, nxt = cur ^ 1;
        __syncthreads();                 // buf[cur] ready; buf[nxt] reads done
        if (ki < 24) {                   // stage chunk ki+1 into buf[nxt]
            ushort4 h;
            h.x = f2h(xa.x); h.y = f2h(xa.y); h.z = f2h(xa.z); h.w = f2h(xa.w);
            *(ushort4*)&xbuf[nxt * 4096 + xoff] = h;
            if (ki < 23) {               // load chunk ki+2 (depth-2)
                const int gk = (ki + 2) * 32 + xk;
                const int ga = (gk <= 780) ? gk : 780;   // Wi packs 0 for k>=784
                xa = *(const float4*)(X + xrow + ga);
            }
            IB[nxt] = *(const half8*)(bpIn + (ki + 1) * 32);
        }
        const u16* rb = xbuf + cur * 4096;
#pragma unroll
        for (int mt = 0; mt < 8; ++mt) {
            half8 af = *(const half8*)&rb[mt * 512 + lane * 8];
            ai[mt] = __builtin_amdgcn_mfma_f32_16x16x32_f16(af, IB[cur], ai[mt], 0, 0, 0);
        }
    }

    // layer-0 ks=0 weight prefetch (new Wc layout): tile cg (z0), 8+cg (z1)
    const int rg = wave >> 3, cg = wave & 7;
    const int cl = lane & 31, lh = lane >> 5;
    const u16* bp0 = Wc + (size_t)cg * 16384 + lane * 8;
    const u16* bp1 = bp0 + 8 * 16384;
    half8 B[2][2];
    B[0][0] = *(const half8*)bp0;
    B[0][1] = *(const half8*)bp1;

    // input epilogue: state v0 (k=u), w = 2*tanh(v0) (k=256+u) — NEW layout
    {
        const float bi = b_in[wave * 16 + fl];
        const int u = wave * 16 + fl;
        const int A0 = (u >> 4) * 2048 + ((u >> 3) & 1) * 256 + (u & 7);
#pragma unroll
        for (int mt = 0; mt < 8; ++mt) {
#pragma unroll
            for (int r = 0; r < 4; ++r) {
                float v = ai[mt][r] + bi;
                float w = 2.f * tanh_fast(v);
                const int addr = A0 + (mt >> 1) * 512 +
                                 ((mt & 1) * 16 + kq * 4 + r) * 8;
                state[addr] = f2h(v);
                state[addr + 32768] = f2h(w);
            }
        }
    }

    // ---------------- 8 implicit layers (32x32x16 MFMA) ----------------
    const int uu = cg * 32 + cl;          // this lane's output column u
    const int A0e = (uu >> 4) * 2048 + ((uu >> 3) & 1) * 256 + (uu & 7);
    for (int L = 0; L < 8; ++L) {
        const float ccv0 = cc[L * 512 + uu];
        const float ccv1 = cc[L * 512 + 256 + uu];
        f32x16 acc00, acc01, acc10, acc11;
#pragma unroll
        for (int j = 0; j < 16; ++j) {
            acc00[j] = 0.f; acc01[j] = 0.f; acc10[j] = 0.f; acc11[j] = 0.f;
        }
        __syncthreads();   // state ready
#pragma unroll
        for (int ks = 0; ks < 32; ++ks) {
            const int cur = ks & 1, nxt = cur ^ 1;
            if (ks < 31) {             // prefetch next K-step (2 x 16B)
                B[nxt][0] = *(const half8*)(bp0 + (ks + 1) * 512);
                B[nxt][1] = *(const half8*)(bp1 + (ks + 1) * 512);
            } else {                   // prefetch next layer's ks=0 across epilogue
                bp0 += 262144; bp1 += 262144;
                if (L < 7) {
                    B[nxt][0] = *(const half8*)bp0;
                    B[nxt][1] = *(const half8*)bp1;
                }
            }
            half8 af0 = *(const half8*)&state[ks * 2048 + (rg * 2 + 0) * 512 + lane * 8];
            half8 af1 = *(const half8*)&state[ks * 2048 + (rg * 2 + 1) * 512 + lane * 8];
            acc00 = __builtin_amdgcn_mfma_f32_32x32x16_f16(af0, B[cur][0], acc00, 0, 0, 0);
            acc10 = __builtin_amdgcn_mfma_f32_32x32x16_f16(af1, B[cur][0], acc10, 0, 0, 0);
            acc01 = __builtin_amdgcn_mfma_f32_32x32x16_f16(af0, B[cur][1], acc01, 0, 0, 0);
            acc11 = __builtin_amdgcn_mfma_f32_32x32x16_f16(af1, B[cur][1], acc11, 0, 0, 0);
        }
        __syncthreads();   // all state reads done; safe to overwrite
        // epilogue: lane owns col u for rows rg*64..+63; z0/z1 in-thread
#pragma unroll
        for (int rt = 0; rt < 2; ++rt) {
#pragma unroll
            for (int j = 0; j < 16; ++j) {
                const int rowt = (j & 3) + 8 * (j >> 2) + 4 * lh;
                const int addr = A0e + (rg * 2 + rt) * 512 + rowt * 8;
                float z0 = (rt ? acc10[j] : acc00[j]) + ccv0;
                float z1 = (rt ? acc11[j] : acc01[j]) + ccv1;
                float tv = tanh_fast(z0);
                state[addr] = f2h(z0);
                state[addr + 32768] = f2h(z1 + tv);
            }
        }
    }

    // ---------------- output stage: out = v0 @ W_out + b_out (32x32x16) ----
    __syncthreads();
    if (wave < 4) {
        f32x16 oa;
#pragma unroll
        for (int j = 0; j < 16; ++j) oa[j] = 0.f;
        const u16* wp = WoT + lane * 8;
#pragma unroll
        for (int ks = 0; ks < 16; ++ks) {          // v0 = state k<256
            half8 af = *(const half8*)&state[ks * 2048 + wave * 512 + lane * 8];
            half8 bf = *(const half8*)(wp + ks * 512);
            oa = __builtin_amdgcn_mfma_f32_32x32x16_f16(af, bf, oa, 0, 0, 0);
        }
        if (cl < 10) {
            const float bv = bo[cl];
#pragma unroll
            for (int j = 0; j < 16; ++j) {
                const int m = wave * 32 + (j & 3) + 8 * (j >> 2) + 4 * lh;
                out[(size_t)(b0 + m) * 10 + cl] = oa[j] + bv;
            }
        }
    }
}

// ============================================================================
// Prep — R14 verbatim (best measured: ~215us), except: pack_wcomb stores in
// the new Wc tile layout; WoT pack is the 32x32x16 B-frag layout (8192 u16).
// ============================================================================

template<int NS>
__device__ __forceinline__ float4 ldn(const float* __restrict__ p, size_t idx) {
    float4 v = *(const float4*)(p + idx);
#pragma unroll
    for (int s = 1; s < NS; ++s) {
        float4 w = *(const float4*)(p + idx + (size_t)s * HS);
        v.x += w.x; v.y += w.y; v.z += w.z; v.w += w.w;
    }
    return v;
}

template<int EPI, int KLEN, int AS, int BS, int ES, int E2S>
__device__ __forceinline__ void gemm_body(float* __restrict__ D,
        const float* __restrict__ A, const float* __restrict__ Bm,
        const float* __restrict__ E, const float* __restrict__ E2,
        const float* __restrict__ scr_r, float* __restrict__ scr_w,
        int i, int u0, int v0, int kh)
{
    __shared__ float As[16][64];
    __shared__ float Bs[16][64];
    const size_t off = (size_t)i * 65536;
    const int t  = threadIdx.x;
    const int tx = t & 15, ty = t >> 4;
    const int lk = t >> 4, lv = (t & 15) << 2;

    float ca = 0.f, cb = 0.f;
    if (EPI == 3 || EPI == 4) {        // NS seed coefficients from rowsum parts
        float* red = &As[0][0];
        {
            float s = scr_r[i * 1024 + t];
#pragma unroll
            for (int vt = 1; vt < 4; ++vt) s += scr_r[i * 1024 + vt * 256 + t];
            red[t] = s;
        }
        __syncthreads();
        for (int o = 128; o >= 1; o >>= 1) {
            if (t < o) red[t] = fmaxf(red[t], red[t + o]);
            __syncthreads();
        }
        const float bt_ = red[0];                  // >= lambda_max; lambda_min >= 2
        const float r = (2.f + bt_) * (2.f + bt_) / (8.f * bt_);
        const float e = (r - 1.f) / (r + 1.f);
        cb = -(1.f - e) / (2.f * bt_);
        ca = -cb * (2.f + bt_);
        __syncthreads();
    }

    const int kb = kh * KLEN;
    float acc[4][4];
#pragma unroll
    for (int m = 0; m < 4; ++m)
#pragma unroll
        for (int n = 0; n < 4; ++n) acc[m][n] = 0.f;

    float4 an = ldn<AS>(A, off + (size_t)(kb + lk) * 256 + u0 + lv);
    float4 bn = ldn<BS>(Bm, off + (size_t)(kb + lk) * 256 + v0 + lv);

    for (int k0 = 0; k0 < KLEN; k0 += 16) {
        if (k0) __syncthreads();
        *(float4*)&As[lk][lv] = an;
        *(float4*)&Bs[lk][lv] = bn;
        if (k0 < KLEN - 16) {
            an = ldn<AS>(A, off + (size_t)(kb + k0 + 16 + lk) * 256 + u0 + lv);
            bn = ldn<BS>(Bm, off + (size_t)(kb + k0 + 16 + lk) * 256 + v0 + lv);
        }
        __syncthreads();
#pragma unroll
        for (int kk = 0; kk < 16; ++kk) {
            float af[4], bf[4];
            *(float4*)&af[0] = *(const float4*)&As[kk][ty * 4];
            *(float4*)&bf[0] = *(const float4*)&Bs[kk][tx * 4];
#pragma unroll
            for (int m = 0; m < 4; ++m)
#pragma unroll
                for (int n = 0; n < 4; ++n) acc[m][n] += af[m] * bf[n];
        }
    }

    float* Dp = D + (size_t)kh * HS;
#pragma unroll
    for (int m = 0; m < 4; ++m) {
        const int u = u0 + ty * 4 + m;
        const size_t idx = off + (size_t)u * 256 + v0 + tx * 4;
        float4 r; float* rf = &r.x;
        if (EPI == 0) {
#pragma unroll
            for (int n = 0; n < 4; ++n) rf[n] = acc[m][n];
        } else if (EPI == 1) {
#pragma unroll
            for (int n = 0; n < 4; ++n)
                rf[n] = acc[m][n] + ((u == v0 + tx * 4 + n) ? 2.f : 0.f);
        } else if (EPI == 2) {
            if (kh == 0) {
                float4 e4 = ldn<ES>(E, idx); const float* ef = &e4.x;
#pragma unroll
                for (int n = 0; n < 4; ++n) rf[n] = 2.f * ef[n] - acc[m][n];
            } else {
#pragma unroll
                for (int n = 0; n < 4; ++n) rf[n] = -acc[m][n];
            }
        } else if (EPI == 3) {
            if (kh == 0) {
                float4 e4 = ldn<ES>(E, idx); const float* ef = &e4.x;
#pragma unroll
                for (int n = 0; n < 4; ++n) rf[n] = ca * ef[n] + cb * acc[m][n];
            } else {
#pragma unroll
                for (int n = 0; n < 4; ++n) rf[n] = cb * acc[m][n];
            }
        } else {   // EPI 4
            if (kh == 0) {
                float4 e4 = ldn<ES>(E, idx); const float* ef = &e4.x;
                float4 f4 = ldn<E2S>(E2, idx); const float* ff = &f4.x;
#pragma unroll
                for (int n = 0; n < 4; ++n)
                    rf[n] = 2.f * ca * ((u == v0 + tx * 4 + n) ? 1.f : 0.f)
                          + 2.f * cb * ef[n] - ca * ff[n] - cb * acc[m][n];
            } else {
#pragma unroll
                for (int n = 0; n < 4; ++n) rf[n] = -cb * acc[m][n];
            }
        }
        *(float4*)&Dp[idx] = r;
        if (EPI == 1) {                // Gershgorin rowsum partial (plain store)
            float s = fabsf(rf[0]) + fabsf(rf[1]) + fabsf(rf[2]) + fabsf(rf[3]);
            s += __shfl_xor(s, 1); s += __shfl_xor(s, 2);
            s += __shfl_xor(s, 4); s += __shfl_xor(s, 8);
            if (tx == 0) scr_w[(i * 4 + (v0 >> 6)) * 256 + u] = s;
        }
    }
}

// K1: C = B0^T B0 + 2I (unsplit, rowsum parts) | Bt | Wi pack | WoT pack
__launch_bounds__(256)
__global__ void k1_fused(const float* __restrict__ B0, const float* __restrict__ W_in,
                         const float* __restrict__ W_out,
                         float* __restrict__ C, float* __restrict__ Bt,
                         u16* __restrict__ Wi, u16* __restrict__ WoT,
                         float* __restrict__ scr)
{
    const int b = blockIdx.x;
    const int t = threadIdx.x;
    if (b < 128) {
        const int i = b >> 4, tile = b & 15;
        gemm_body<1, 256, 1, 1, 1, 1>(C, B0, B0, nullptr, nullptr,
                                      nullptr, scr, i,
                                      (tile >> 2) * 64, (tile & 3) * 64, 0);
        return;
    }
    __shared__ float tl[32][33];
    const int tx = t & 31, ty = t >> 5;   // 32 x 8
    if (b < 192) {                        // Bt transpose: 64 blocks
        const int bb = b - 128;
        const int i = bb >> 3;
        const size_t off = (size_t)i * 65536;
        const int u0 = (bb & 7) * 32;
        for (int k0 = 0; k0 < 256; k0 += 32) {
            __syncthreads();
#pragma unroll
            for (int r = 0; r < 32; r += 8)
                tl[ty + r][tx] = B0[off + (size_t)(u0 + ty + r) * 256 + k0 + tx];
            __syncthreads();
#pragma unroll
            for (int r = 0; r < 32; r += 8)
                Bt[off + (size_t)(k0 + ty + r) * 256 + u0 + tx] = tl[tx][ty + r];
        }
    } else if (b < 392) {                 // Wi pack: 200 blocks
        const int bb = b - 192;           // 25 k-tiles x 8 u-tiles
        const int k0 = (bb % 25) * 32, u0 = (bb / 25) * 32;
#pragma unroll
        for (int r = 0; r < 32; r += 8) {
            const int k = k0 + ty + r;
            tl[ty + r][tx] = (k < 784) ? W_in[(size_t)k * 256 + u0 + tx] : 0.f;
        }
        __syncthreads();
#pragma unroll
        for (int r = 0; r < 32; r += 8)
            Wi[(size_t)(u0 + ty + r) * 800 + k0 + tx] = f2h(tl[tx][ty + r]);
    } else {                              // WoT pack: [16 ks][512] B-frag order
        for (int idx = t; idx < 8192; idx += 256) {
            const int ks = idx >> 9, rr = idx & 511;
            const int l = rr >> 3, j = rr & 7;
            const int col = l & 31;
            const int k = ks * 16 + (l >> 5) * 8 + j;
            WoT[idx] = f2h((col < 10) ? W_out[(size_t)k * 10 + col] : 0.f);
        }
    }
}

// split GEMM dispatch: grid (4,4,32), z = matrix(0..7) + 8*kq (kq 0..3), K=64
template<int EPI, int AS, int BS, int ES, int E2S>
__launch_bounds__(256)
__global__ void gemmS(float* __restrict__ D, const float* __restrict__ A,
                      const float* __restrict__ Bm, const float* __restrict__ E,
                      const float* __restrict__ E2, const float* __restrict__ scr)
{
    const int z = blockIdx.z;
    gemm_body<EPI, 64, AS, BS, ES, E2S>(D, A, Bm, E, E2, scr, nullptr,
                                        z & 7, blockIdx.y * 64, blockIdx.x * 64,
                                        z >> 3);
}

// PQcc: z<16: P = M Bt (split2) | z 16..31: Q = B M (split2) | z==32: cc
__launch_bounds__(256)
__global__ void gemmPQcc(float* __restrict__ bufPQ, const float* __restrict__ M,
                         const float* __restrict__ Bt, const float* __restrict__ B0,
                         const float* __restrict__ q, float* __restrict__ cc)
{
    const int z = blockIdx.z;
    if (z < 16) {
        gemm_body<0, 128, 4, 1, 1, 1>(bufPQ, M, Bt, nullptr, nullptr, nullptr,
                nullptr, z & 7, blockIdx.y * 64, blockIdx.x * 64, (z >> 3) & 1);
        return;
    }
    if (z < 32) {
        const int zz = z - 16;
        gemm_body<0, 128, 1, 4, 1, 1>(bufPQ + 2 * (size_t)HS, Bt, M, nullptr,
                nullptr, nullptr, nullptr, zz & 7,
                blockIdx.y * 64, blockIdx.x * 64, (zz >> 3) & 1);
        return;
    }
    if (blockIdx.y != 0 || blockIdx.x >= 8) return;
    __shared__ float qs[256];
    __shared__ float vs[256];
    __shared__ float c1s[256];
    const int i = blockIdx.x;
    const int u = threadIdx.x;
    const size_t ob = (size_t)i * 65536;
    qs[u] = q[i * 256 + u];
    __syncthreads();
    float s0 = 0.f;
    for (int k = 0; k < 256; ++k) s0 += B0[ob + (size_t)k * 256 + u] * qs[k];
    vs[u] = 0.1f * s0;
    __syncthreads();
    float s = 0.f;
    for (int k = 0; k < 256; ++k) {
        const size_t mi = ob + (size_t)k * 256 + u;
        s += (M[mi] + M[mi + HS] + M[mi + 2 * (size_t)HS] + M[mi + 3 * (size_t)HS]) * vs[k];
    }
    c1s[u] = s;
    cc[i * 512 + 256 + u] = s;
    __syncthreads();
    float s2 = 0.f;
    for (int k = 0; k < 256; ++k) s2 += Bt[ob + (size_t)k * 256 + u] * c1s[k];
    cc[i * 512 + u] = 0.1f * qs[u] - s2;
}

// Wc pack into the NEW tile layout; sums partials (P s2, Q s2, R s4, M s4)
__launch_bounds__(256)
__global__ void pack_wcomb(const float* __restrict__ P, const float* __restrict__ Q,
                           const float* __restrict__ R, const float* __restrict__ M,
                           u16* __restrict__ W)
{
    const int i = blockIdx.y;
    const int e = blockIdx.x * 256 + threadIdx.x;   // 0..262143
    const int c = e >> 9, k = e & 511;
    const size_t off = (size_t)i * 65536;
    float v;
    if (c < 256) {        // z0 row u=c: [I - R | -Q]
        if (k < 256) {
            const size_t idx = off + (size_t)c * 256 + k;
            v = ((c == k) ? 1.f : 0.f)
              - (R[idx] + R[idx + HS] + R[idx + 2 * (size_t)HS] + R[idx + 3 * (size_t)HS]);
        } else {
            const size_t idx = off + (size_t)c * 256 + (k - 256);
            v = -(Q[idx] + Q[idx + HS]);
        }
    } else {              // z1 row u=c-256: [P | M]
        const int u = c - 256;
        if (k < 256) {
            const size_t idx = off + (size_t)u * 256 + k;
            v = P[idx] + P[idx + HS];
        } else {
            const size_t idx = off + (size_t)u * 256 + (k - 256);
            v = M[idx] + M[idx + HS] + M[idx + 2 * (size_t)HS] + M[idx + 3 * (size_t)HS];
        }
    }
    // store at B-frag tile layout: tile = col-group (z0: c>>5, z1: 8+((c-256)>>5))
    const int tile = (c < 256) ? (c >> 5) : (8 + ((c - 256) >> 5));
    const int cl2 = c & 31;
    const size_t wadr = (size_t)i * 262144 + (size_t)tile * 16384
                      + (size_t)(k >> 4) * 512 + ((k >> 3) & 1) * 256 + cl2 * 8 + (k & 7);
    W[wadr] = f2h(v);
}

extern "C" void kernel_launch(void* const* d_in, const int* in_sizes, int n_in,
                              void* d_out, int out_size, void* d_ws, size_t ws_size,
                              hipStream_t stream)
{
    const float* x     = (const float*)d_in[0];
    const float* W_in  = (const float*)d_in[1];
    const float* b_in  = (const float*)d_in[2];
    const float* B0    = (const float*)d_in[3];
    const float* q     = (const float*)d_in[4];
    const float* W_out = (const float*)d_in[5];
    const float* b_out = (const float*)d_in[6];

    u16* Wc  = (u16*)d_ws;                 // 8 * 262144 u16 = 4 MB
    u16* Wi  = Wc + 8 * 262144;            // 256*800 u16
    u16* WoT = Wi + 204800;                // 8192 u16
    float* cc = (float*)(WoT + 8192);      // 8*512 floats
    float* F  = cc + 4096;
    float* Cm   = F;                       // unsplit (1 HS)
    float* Bt   = F + 1 * HS;              // unsplit (1 HS)
    float* bufY = F + 2 * HS;              // 4 HS: Y1 / Y2 / Y3 / {P,Q}
    float* bufXa = F + 6 * HS;             // 4 HS: X1 / M
    float* bufXb = F + 10 * HS;            // 4 HS: X2 / R
    float* scr  = F + 14 * HS;             // 8192 floats (rowsum partials)

    // K1: C = B0^T B0 + 2I (+rowsum parts) | Bt | Wi | WoT
    k1_fused<<<393, 256, 0, stream>>>(B0, W_in, W_out, Cm, Bt, Wi, WoT, scr);
    // NS iteration 1 with virtual X0 = aI + bC:
    gemmS<3, 1, 1, 1, 1><<<dim3(4, 4, 32), 256, 0, stream>>>(
        bufY, Cm, Cm, Cm, nullptr, scr);                    // Y1 = aC + bC^2
    gemmS<4, 1, 4, 1, 4><<<dim3(4, 4, 32), 256, 0, stream>>>(
        bufXa, Cm, bufY, Cm, bufY, scr);                    // X1 = 2X0 - X0*Y1
    // NS iteration 2:
    gemmS<0, 1, 4, 1, 1><<<dim3(4, 4, 32), 256, 0, stream>>>(
        bufY, Cm, bufXa, nullptr, nullptr, nullptr);        // Y2 = C*X1
    gemmS<2, 4, 4, 4, 1><<<dim3(4, 4, 32), 256, 0, stream>>>(
        bufXb, bufXa, bufY, bufXa, nullptr, nullptr);       // X2 = 2X1 - X1*Y2
    // NS iteration 3:
    gemmS<0, 1, 4, 1, 1><<<dim3(4, 4, 32), 256, 0, stream>>>(
        bufY, Cm, bufXb, nullptr, nullptr, nullptr);        // Y3 = C*X2
    gemmS<2, 4, 4, 4, 1><<<dim3(4, 4, 32), 256, 0, stream>>>(
        bufXa, bufXb, bufY, bufXb, nullptr, nullptr);       // M = 2X2 - X2*Y3
    // P = M B^T (s2) | Q = B M (s2) | cc:
    gemmPQcc<<<dim3(4, 4, 33), 256, 0, stream>>>(bufY, bufXa, Bt, B0, q, cc);
    // R = B P (s4):
    gemmS<0, 1, 2, 1, 1><<<dim3(4, 4, 32), 256, 0, stream>>>(
        bufXb, Bt, bufY, nullptr, nullptr, nullptr);        // R
    // pack (P=bufY, Q=bufY+2HS, R=bufXb, M=bufXa):
    pack_wcomb<<<dim3(1024, 8), 256, 0, stream>>>(
        bufY, bufY + 2 * (size_t)HS, bufXb, bufXa, Wc);

    // ---- the whole network in one kernel ----
    meganet<<<BATCH_N / 128, 1024, 0, stream>>>(
        x, Wi, b_in, Wc, cc, WoT, b_out, (float*)d_out);
}